// Round 1
// 312.190 us; speedup vs baseline: 1.0703x; 1.0703x over previous
//
#include <hip/hip_runtime.h>

// Problem constants
#define CV   34          // C*V channels
#define TTOT 2048        // T
#define NB   512         // batches
#define XB   69632       // x per-batch stride (2*2048*17)
#define XC   34816       // x per-co stride (2048*17)

// Workspace layout (floats)
#define GS_STRIDE 1192                   // per-batch: G (1156) + s0 (34) + pad
#define RB_OFF    (512 * 1192)           // region B offset
// region B per batch: 1024 ushort (hi/lo bf16 planes, 16x32) = 512 f,
// then cy[16], wy32[16], wy33[16] f32 -> 560 f, padded to 576
#define RB_STRIDE 576

typedef __attribute__((ext_vector_type(8))) short v8s;   // 8 x bf16 (MFMA A/B frag)
typedef __attribute__((ext_vector_type(4))) float v4f;   // 4 x f32 (MFMA C/D frag)

__device__ __forceinline__ unsigned short f2bf(float f) {
    unsigned int u = __float_as_uint(f);
    u = u + 0x7FFFu + ((u >> 16) & 1u);   // round-to-nearest-even
    return (unsigned short)(u >> 16);
}
__device__ __forceinline__ float bf2f(unsigned short s) {
    return __uint_as_float(((unsigned int)s) << 16);
}

__device__ __forceinline__ unsigned int cvtpk_bf16(float a, float b) {
    unsigned int r;   // r.lo16 = bf16(a), r.hi16 = bf16(b), RNE
    asm("v_cvt_pk_bf16_f32 %0, %1, %2" : "=v"(r) : "v"(a), "v"(b));
    return r;
}

// split 8 f32 -> packed hi/lo bf16 MFMA fragments (RNE; residual exact in f32)
__device__ __forceinline__ void split8(const float (&f)[8], v8s* hi, v8s* lo) {
    union { unsigned int u[4]; v8s s; } H, L;
#pragma unroll
    for (int p = 0; p < 4; ++p) {
        float a = f[2 * p], b = f[2 * p + 1];
        unsigned int h = cvtpk_bf16(a, b);
        float ra = a - __uint_as_float(h << 16);
        float rb = b - __uint_as_float(h & 0xFFFF0000u);
        L.u[p] = cvtpk_bf16(ra, rb);
        H.u[p] = h;
    }
    *hi = H.s;
    *lo = L.s;
}

// async-stage one 128-t chunk (2 co x 2176 floats, verbatim global order) to LDS.
// 17 x global_load_lds(16B); wave w issues instrs {w, w+4, ...}.
__device__ __forceinline__ void stage_chunk(const float* __restrict__ xb, int t0,
                                            float* rawbuf, int w, int lane) {
#pragma unroll
    for (int i = 0; i < 5; ++i) {
        int idx = i * 4 + w;
        if (idx < 17) {
            int fl = idx * 256 + lane * 4;
            int co = (fl >= 2176) ? 1 : 0;
            const float* g = xb + t0 * 17 + fl + co * 32640;   // 32640 = XC - 2176
            __builtin_amdgcn_global_load_lds(
                (const __attribute__((address_space(1))) void*)g,
                (__attribute__((address_space(3))) void*)(rawbuf + idx * 256),
                16, 0, 0);
        }
    }
}

// ---------------------------------------------------------------------------
// K1: per-(batch, t-segment) partial Gram G += Hseg Hseg^T (34x34) and s0.
// Async f32 staging (double-buffered) + in-register hi/lo split at frag build.
// ---------------------------------------------------------------------------
struct SmemGramB {
    float Gpart[4][34][36];
    float spart[4][36];
};

__global__ __launch_bounds__(256, 4) void k_gram(const float* __restrict__ x,
                                                 float* __restrict__ ws) {
    __shared__ __align__(16) union {
        float raw[2][4352];      // 2 x (2 co x 2176 f32)  = 34,816 B
        SmemGramB b;             // epilogue reduction area = 20,160 B
    } sm;

    const int b    = blockIdx.x >> 2;
    const int seg  = blockIdx.x & 3;          // 4 segments of 512 t
    const int tid  = threadIdx.x;
    const int l    = tid & 63;
    const int w    = tid >> 6;                // wave id 0..3 -> k-slice in chunk
    const int row16 = l & 15;
    const int quad  = l >> 4;
    const float* xb = x + (size_t)b * XB;
    const int t0 = seg * 512;

    // per-lane dword offsets for channel c = r*16+row16 (clamped: rows 34..47
    // duplicate row 33; their MFMA outputs land in discarded C rows/cols)
    int offc[3];
#pragma unroll
    for (int r = 0; r < 3; ++r) {
        int c = r * 16 + row16;
        if (c > 33) c = 33;
        offc[r] = (c >= 17) ? (2159 + c) : c;   // = co*2176 + v
    }
    const int koff = w * 32 + quad * 8;        // t offset within 128-t chunk

    v4f accG[3][3];
    v4f accS[3];
    v4f vz = {0.f, 0.f, 0.f, 0.f};
#pragma unroll
    for (int r = 0; r < 3; ++r) {
        accS[r] = vz;
#pragma unroll
        for (int c = 0; c < 3; ++c) accG[r][c] = vz;
    }
    v8s ones;
#pragma unroll
    for (int i = 0; i < 8; ++i) ones[i] = (short)0x3F80;   // bf16 1.0

    stage_chunk(xb, t0, sm.raw[0], w, l);
    __syncthreads();                           // drains vmcnt(0): chunk 0 ready

    for (int ch = 0; ch < 4; ++ch) {           // 4 chunks of 128 t
        const int cur = ch & 1;
        if (ch < 3) stage_chunk(xb, t0 + (ch + 1) * 128, sm.raw[cur ^ 1], w, l);

        const float* rb = sm.raw[cur] + koff * 17;
        v8s fh[3], fl4[3];
#pragma unroll
        for (int r = 0; r < 3; ++r) {
            const float* p = rb + offc[r];
            float f[8];
#pragma unroll
            for (int e = 0; e < 8; ++e) f[e] = p[e * 17];   // 8 x ds_read_b32, imm offs
            split8(f, &fh[r], &fl4[r]);
        }
#pragma unroll
        for (int r = 0; r < 3; ++r) {
#pragma unroll
            for (int c = 0; c < 3; ++c) {
                accG[r][c] = __builtin_amdgcn_mfma_f32_16x16x32_bf16(fh[r],  fh[c],  accG[r][c], 0, 0, 0);
                accG[r][c] = __builtin_amdgcn_mfma_f32_16x16x32_bf16(fh[r],  fl4[c], accG[r][c], 0, 0, 0);
                accG[r][c] = __builtin_amdgcn_mfma_f32_16x16x32_bf16(fl4[r], fh[c],  accG[r][c], 0, 0, 0);
            }
            accS[r] = __builtin_amdgcn_mfma_f32_16x16x32_bf16(fh[r],  ones, accS[r], 0, 0, 0);
            accS[r] = __builtin_amdgcn_mfma_f32_16x16x32_bf16(fl4[r], ones, accS[r], 0, 0, 0);
        }
        __syncthreads();   // drains next-chunk stage; protects buffer reuse
    }

    // epilogue: union switched to sm.b (all raw reads complete + barrier passed)
#pragma unroll
    for (int r = 0; r < 3; ++r) {
#pragma unroll
        for (int c = 0; c < 3; ++c) {
#pragma unroll
            for (int i = 0; i < 4; ++i) {
                int m = r * 16 + quad * 4 + i;
                int n = c * 16 + row16;
                if (m < 34 && n < 34) sm.b.Gpart[w][m][n] = accG[r][c][i];
            }
        }
        if (row16 == 0) {
#pragma unroll
            for (int i = 0; i < 4; ++i) {
                int m = r * 16 + quad * 4 + i;
                if (m < 34) sm.b.spart[w][m] = accS[r][i];
            }
        }
    }
    __syncthreads();
    float* gout = ws + (size_t)b * GS_STRIDE;
    for (int idx = tid; idx < 1156; idx += 256) {
        int m = idx / 34, n = idx - m * 34;
        atomicAdd(&gout[idx], sm.b.Gpart[0][m][n] + sm.b.Gpart[1][m][n] +
                              sm.b.Gpart[2][m][n] + sm.b.Gpart[3][m][n]);
    }
    if (tid < 34)
        atomicAdd(&gout[1156 + tid], sm.b.spart[0][tid] + sm.b.spart[1][tid] +
                                     sm.b.spart[2][tid] + sm.b.spart[3][tid]);
}

// ---------------------------------------------------------------------------
// K2: per-batch affine chain (unchanged structure; stage7 emits compact
// region-B: 16x32 bf16 hi/lo planes + f32 {cy, wy[:,32], wy[:,33]}).
// ---------------------------------------------------------------------------

// 2x4-tile mm on LDS: D[i][j] = sum_e L[i][e]*R[j][e], 153 threads, K=36 (pads zero)
__device__ __forceinline__ void mm24(const float L[][36], const float R[][36],
                                     float D[][36], int u) {
    int ti = u / 9, tj = u - ti * 9;      // u < 153
    int i0 = ti * 2, j0 = tj * 4;
    float acc[2][4] = {};
    for (int e0 = 0; e0 < 36; e0 += 4) {
        float4 lv[2], rv[4];
        lv[0] = *(const float4*)&L[i0][e0];
        lv[1] = *(const float4*)&L[i0 + 1][e0];
#pragma unroll
        for (int c = 0; c < 4; ++c) rv[c] = *(const float4*)&R[j0 + c][e0];
#pragma unroll
        for (int a = 0; a < 2; ++a)
#pragma unroll
            for (int c = 0; c < 4; ++c)
                acc[a][c] += lv[a].x * rv[c].x + lv[a].y * rv[c].y +
                             lv[a].z * rv[c].z + lv[a].w * rv[c].w;
    }
#pragma unroll
    for (int a = 0; a < 2; ++a)
#pragma unroll
        for (int c = 0; c < 4; ++c) D[i0 + a][j0 + c] = acc[a][c];
}

// 4x4-tile mm, L from global (row stride 34, K=34), 81 threads.
__device__ __forceinline__ void mmG4(const float* __restrict__ Lg,
                                     const float R[][36], float D[][36],
                                     int transpose, int u) {
    int ti = u / 9, tj = u - ti * 9;      // u < 81
    int i0 = ti * 4, j0 = tj * 4;
    float acc[4][4] = {};
    for (int e0 = 0; e0 < 32; e0 += 4) {
        float2 la[4], lb[4];
        float4 rv[4];
#pragma unroll
        for (int a = 0; a < 4; ++a) {
            int ri = i0 + a; ri = ri < 34 ? ri : 33;   // clamp: row 34/35 loads
            la[a] = *(const float2*)(Lg + ri * 34 + e0);
            lb[a] = *(const float2*)(Lg + ri * 34 + e0 + 2);
        }
#pragma unroll
        for (int c = 0; c < 4; ++c) rv[c] = *(const float4*)&R[j0 + c][e0];
#pragma unroll
        for (int a = 0; a < 4; ++a)
#pragma unroll
            for (int c = 0; c < 4; ++c)
                acc[a][c] += la[a].x * rv[c].x + la[a].y * rv[c].y +
                             lb[a].x * rv[c].z + lb[a].y * rv[c].w;
    }
    {   // tail e = 32,33
        float2 la[4];
#pragma unroll
        for (int a = 0; a < 4; ++a) {
            int ri = i0 + a; ri = ri < 34 ? ri : 33;
            la[a] = *(const float2*)(Lg + ri * 34 + 32);
        }
#pragma unroll
        for (int c = 0; c < 4; ++c) {
            float r0 = R[j0 + c][32], r1 = R[j0 + c][33];
#pragma unroll
            for (int a = 0; a < 4; ++a) acc[a][c] += la[a].x * r0 + la[a].y * r1;
        }
    }
#pragma unroll
    for (int a = 0; a < 4; ++a) {
        if (i0 + a < 34) {
#pragma unroll
            for (int c = 0; c < 4; ++c) {
                if (transpose) D[j0 + c][i0 + a] = acc[a][c];
                else           D[i0 + a][j0 + c] = acc[a][c];
            }
        }
    }
}

__global__ __launch_bounds__(256) void k_chain(
    const float* __restrict__ wq, const float* __restrict__ bq,
    const float* __restrict__ wk, const float* __restrict__ bk,
    const float* __restrict__ wv, const float* __restrict__ bv,
    const float* __restrict__ w1, const float* __restrict__ b1,
    const float* __restrict__ gamma, const float* __restrict__ beta,
    const float* __restrict__ mean, const float* __restrict__ var,
    float* __restrict__ ws) {
    __shared__ float G0b[36][36], At[36][36], Aq[36][36], Ak[36][36],
        AvT[36][36], S1[36][36], Sc[36][36];
    __shared__ float s0v[36], a_[36], aq_[36], ak_[36], avv_[36],
        qs_[36], ks_[36], invv[16];

    const int tid = threadIdx.x;
    const int b   = blockIdx.x;
    const float* gsb = ws + (size_t)b * GS_STRIDE;

    // zero all LDS (pads must be 0 and stay 0)
    for (int i = tid; i < 1296; i += 256) {
        int m = i / 36, n = i - m * 36;
        G0b[m][n] = 0; At[m][n] = 0; Aq[m][n] = 0; Ak[m][n] = 0;
        AvT[m][n] = 0; S1[m][n] = 0; Sc[m][n] = 0;
    }
    if (tid < 36) {
        s0v[tid] = 0; a_[tid] = 0; aq_[tid] = 0; ak_[tid] = 0; avv_[tid] = 0;
        qs_[tid] = 0; ks_[tid] = 0;
    }
    __syncthreads();
    // load G0, s0; layer-0 shortcut: A = I  =>  Aq=wq0, Ak=wk0, AvT=wv0^T, aux=b*
    for (int i = tid; i < 1156; i += 256) {
        int m = i / 34, n = i - m * 34;
        G0b[m][n] = gsb[i];
        Aq[m][n] = wq[i]; Ak[m][n] = wk[i]; AvT[n][m] = wv[i];
    }
    if (tid < 34) {
        s0v[tid] = gsb[1156 + tid];
        aq_[tid] = bq[tid]; ak_[tid] = bk[tid]; avv_[tid] = bv[tid];
    }
    __syncthreads();

    for (int lyr = 0; lyr < 3; ++lyr) {
        const float* wql = wq + lyr * 1156;
        const float* wkl = wk + lyr * 1156;
        const float* wvl = wv + lyr * 1156;
        if (lyr > 0) {
            // stage1: Aq = Wq*A, Ak = Wk*A, AvT = (Wv*A)^T  (concurrent)
            if (tid < 243) {
                int g = tid / 81, u = tid - g * 81;
                const float* Lg = (g == 0) ? wql : (g == 1) ? wkl : wvl;
                float (*D)[36] = (g == 0) ? Aq : (g == 1) ? Ak : AvT;
                mmG4(Lg, At, D, g == 2, u);
            }
            __syncthreads();
        }
        // stage2: S1 = Aq*G0 ; aux1: aq_/ak_/avv_ = w*a_ + b  (skip for lyr 0)
        if (tid < 153) {
            mm24(Aq, G0b, S1, tid);
        } else if (lyr > 0 && tid < 255) {
            int u = tid - 153, r = u / 34, c = u - r * 34;
            const float* wrow = ((r == 0) ? wql : (r == 1) ? wkl : wvl) + c * 34;
            float s = 0;
            for (int e = 0; e < 34; ++e) s += wrow[e] * a_[e];
            float bb = (r == 0) ? bq[lyr * 34 + c]
                     : (r == 1) ? bk[lyr * 34 + c] : bv[lyr * 34 + c];
            if (r == 0) aq_[c] = s + bb;
            else if (r == 1) ak_[c] = s + bb;
            else avv_[c] = s + bb;
        }
        __syncthreads();
        // stage3: Sc = S1*Ak^T ; qs_ = Aq*s0, ks_ = Ak*s0
        if (tid < 153) {
            mm24(S1, Ak, Sc, tid);
        } else if (tid >= 160 && tid < 228) {
            int u = tid - 160, r = u / 34, c = u - r * 34;
            const float (*M)[36] = r ? Ak : Aq;
            float s = 0;
            for (int e = 0; e < 34; ++e) s += M[c][e] * s0v[e];
            if (r == 0) qs_[c] = s; else ks_[c] = s;
        }
        __syncthreads();
        // stage4: softmax rows (with rank-1 score corrections)
        if (tid < 34) {
            const int c = tid;
            const float scale = 0.022097086912079608f;   // 1/sqrt(2048)
            float mx = -1e30f;
            for (int d = 0; d < 34; ++d) {
                float v = (Sc[c][d] + qs_[c] * ak_[d] + aq_[c] * ks_[d] +
                           2048.0f * aq_[c] * ak_[d]) * scale;
                Sc[c][d] = v;
                mx = fmaxf(mx, v);
            }
            float sum = 0;
            for (int d = 0; d < 34; ++d) {
                float e = __expf(Sc[c][d] - mx);
                Sc[c][d] = e;
                sum += e;
            }
            float rs = 1.0f / sum;
            for (int d = 0; d < 34; ++d) Sc[c][d] *= rs;
        }
        __syncthreads();
        // stage5: At = AvT * attn^T ; a_ = attn * avv_
        if (tid < 153) {
            mm24(AvT, Sc, At, tid);
        } else if (tid >= 160 && tid < 194) {
            int c = tid - 160;
            float s = 0;
            for (int d = 0; d < 34; ++d) s += Sc[c][d] * avv_[d];
            a_[c] = s;
        }
        __syncthreads();
    }

    // stage6: S1[o][c] = (w1 * A3)[o][c] (o<16) ; invv ; cy_raw -> ks_
    if (tid < 72) {
        int ti = tid / 9, tj = tid - ti * 9;
        int i0 = ti * 2, j0 = tj * 4;
        float acc[2][4] = {};
        for (int e0 = 0; e0 < 32; e0 += 4) {
            float2 la[2], lb[2];
            float4 rv[4];
#pragma unroll
            for (int a = 0; a < 2; ++a) {
                la[a] = *(const float2*)(w1 + (i0 + a) * 34 + e0);
                lb[a] = *(const float2*)(w1 + (i0 + a) * 34 + e0 + 2);
            }
#pragma unroll
            for (int c = 0; c < 4; ++c) rv[c] = *(const float4*)&At[j0 + c][e0];
#pragma unroll
            for (int a = 0; a < 2; ++a)
#pragma unroll
                for (int c = 0; c < 4; ++c)
                    acc[a][c] += la[a].x * rv[c].x + la[a].y * rv[c].y +
                                 lb[a].x * rv[c].z + lb[a].y * rv[c].w;
        }
        {
            float2 la[2];
#pragma unroll
            for (int a = 0; a < 2; ++a)
                la[a] = *(const float2*)(w1 + (i0 + a) * 34 + 32);
#pragma unroll
            for (int c = 0; c < 4; ++c) {
                float r0 = At[j0 + c][32], r1 = At[j0 + c][33];
#pragma unroll
                for (int a = 0; a < 2; ++a) acc[a][c] += la[a].x * r0 + la[a].y * r1;
            }
        }
#pragma unroll
        for (int a = 0; a < 2; ++a)
#pragma unroll
            for (int c = 0; c < 4; ++c) S1[i0 + a][j0 + c] = acc[a][c];
    } else if (tid < 88) {
        int o = tid - 72;
        invv[o] = gamma[o] * rsqrtf(var[o] + 1e-5f);
    } else if (tid < 104) {
        int o = tid - 88;
        float s = 0;
        for (int e = 0; e < 34; ++e) s += w1[o * 34 + e] * a_[e];
        ks_[o] = s + b1[o];          // raw cy
    }
    __syncthreads();
    // stage7: emit compact Wy': bf16 hi/lo planes for c<32, f32 cols 32/33, cy
    float* wb = ws + RB_OFF + (size_t)b * RB_STRIDE;
    if (tid < 16) {
        wb[512 + tid] = (ks_[tid] - mean[tid]) * invv[tid] + beta[tid];   // cy'
    } else if (tid < 48) {
        int u = tid - 16, o = u & 15, cc = u >> 4;          // cc = 0,1
        wb[528 + cc * 16 + o] = S1[o][32 + cc] * invv[o];   // wy32 / wy33 (f32)
    }
    unsigned short* wp = (unsigned short*)wb;
    for (int i = tid; i < 512; i += 256) {
        int o = i >> 5, c = i & 31;
        float vv = S1[o][c] * invv[o];
        unsigned short hb = f2bf(vv);
        wp[i] = hb;
        wp[512 + i] = f2bf(vv - bf2f(hb));
    }
}

// ---------------------------------------------------------------------------
// K3: out = w2 * leaky(Wy' h0 + cy') + b2. Async f32 staging + in-register
// split at B-frag build; channels 32/33 via exact f32 scalar FMA (MFMA halved).
// ---------------------------------------------------------------------------
__global__ __launch_bounds__(256, 4) void k_out(const float* __restrict__ x,
                                                const float* __restrict__ w2,
                                                const float* __restrict__ b2,
                                                const float* __restrict__ ws,
                                                float* __restrict__ out) {
    __shared__ __align__(16) float raw[2][4352];

    const int tid  = threadIdx.x;
    const int b    = blockIdx.x >> 3;
    const int seg  = (blockIdx.x & 7) * 256;
    const int l    = tid & 63;
    const int w    = tid >> 6;
    const int quad = l >> 4;
    const int col  = l & 15;

    const float* wb = ws + RB_OFF + (size_t)b * RB_STRIDE;
    const unsigned short* wp = (const unsigned short*)wb;
    v8s aH = *(const v8s*)&wp[col * 32 + quad * 8];
    v8s aL = *(const v8s*)&wp[512 + col * 32 + quad * 8];
    float cyr[4], w2r[3][4], wy32r[4], wy33r[4];
#pragma unroll
    for (int i = 0; i < 4; ++i) {
        int o = quad * 4 + i;
        cyr[i]   = wb[512 + o];
        wy32r[i] = wb[528 + o];
        wy33r[i] = wb[544 + o];
#pragma unroll
        for (int p = 0; p < 3; ++p) w2r[p][i] = w2[p * 16 + o];
    }
    float b2r[3] = {b2[0], b2[1], b2[2]};
    const float* xb = x + (size_t)b * XB;

    // per-lane dword offsets for channels c = quad*8+e (all real, c < 32)
    int offq[8];
#pragma unroll
    for (int e = 0; e < 8; ++e) {
        int c = quad * 8 + e;
        offq[e] = (c >= 17) ? (2159 + c) : c;   // = co*2176 + v
    }

    stage_chunk(xb, seg, raw[0], w, l);
    __syncthreads();

    for (int ch = 0; ch < 2; ++ch) {
        if (ch == 0) stage_chunk(xb, seg + 128, raw[1], w, l);
        for (int tt = w; tt < 8; tt += 4) {
            const int tl = tt * 16 + col;
            const float* rbt = raw[ch] + tl * 17;
            float f[8];
#pragma unroll
            for (int e = 0; e < 8; ++e) f[e] = rbt[offq[e]];
            v8s bH, bL;
            split8(f, &bH, &bL);
            v4f acc = {0.f, 0.f, 0.f, 0.f};
            acc = __builtin_amdgcn_mfma_f32_16x16x32_bf16(aH, bH, acc, 0, 0, 0);
            acc = __builtin_amdgcn_mfma_f32_16x16x32_bf16(aH, bL, acc, 0, 0, 0);
            acc = __builtin_amdgcn_mfma_f32_16x16x32_bf16(aL, bH, acc, 0, 0, 0);
            float h32 = rbt[2191];   // c=32 (co1, v15) — LDS broadcast across quads
            float h33 = rbt[2192];   // c=33 (co1, v16)
            float op[3] = {0, 0, 0};
#pragma unroll
            for (int i = 0; i < 4; ++i) {
                float y = acc[i] + cyr[i] + wy32r[i] * h32 + wy33r[i] * h33;
                float z = (y > 0.f) ? y : 0.01f * y;
#pragma unroll
                for (int p = 0; p < 3; ++p) op[p] += w2r[p][i] * z;
            }
#pragma unroll
            for (int p = 0; p < 3; ++p) {
                op[p] += __shfl_xor(op[p], 16);
                op[p] += __shfl_xor(op[p], 32);
            }
            if (l < 16) {
                int tg = seg + ch * 128 + tt * 16 + l;
#pragma unroll
                for (int p = 0; p < 3; ++p)
                    out[((size_t)b * 3 + p) * 2048 + tg] = op[p] + b2r[p];
            }
        }
        __syncthreads();   // drains chunk-1 stage; protects buffer before exit
    }
}

extern "C" void kernel_launch(void* const* d_in, const int* in_sizes, int n_in,
                              void* d_out, int out_size, void* d_ws, size_t ws_size,
                              hipStream_t stream) {
    const float* x     = (const float*)d_in[0];
    const float* wq    = (const float*)d_in[1];
    const float* bq    = (const float*)d_in[2];
    const float* wk    = (const float*)d_in[3];
    const float* bk    = (const float*)d_in[4];
    const float* wv    = (const float*)d_in[5];
    const float* bv    = (const float*)d_in[6];
    const float* w1    = (const float*)d_in[7];
    const float* b1    = (const float*)d_in[8];
    const float* gamma = (const float*)d_in[9];
    const float* beta  = (const float*)d_in[10];
    const float* mean  = (const float*)d_in[11];
    const float* var   = (const float*)d_in[12];
    const float* w2    = (const float*)d_in[13];
    const float* b2    = (const float*)d_in[14];
    float* ws  = (float*)d_ws;
    float* out = (float*)d_out;

    hipMemsetAsync(d_ws, 0, (size_t)NB * GS_STRIDE * sizeof(float), stream);
    k_gram<<<dim3(2048), dim3(256), 0, stream>>>(x, ws);
    k_chain<<<dim3(512), dim3(256), 0, stream>>>(wq, bq, wk, bk, wv, bv,
                                                 w1, b1, gamma, beta, mean, var, ws);
    k_out<<<dim3(4096), dim3(256), 0, stream>>>(x, w2, b2, ws, out);
}